// Round 2
// baseline (682.802 us; speedup 1.0000x reference)
//
#include <hip/hip_runtime.h>
#include <stdint.h>

// WinnerCombiner: B=64, L=4096, K=64
#define DECAY   0.6065306597126334f   // f32(e^-0.5), same literal as passing r1 kernel
#define GAIN    0.5f

#define B_DIM 64
#define L_DIM 4096
#define K_DIM 64

// 6-level DPP max; result valid in lane 63 (all inputs >= 0, bound_ctrl 0-fill safe)
__device__ __forceinline__ float wave_max_to63(float x) {
    int v;
    v = __builtin_amdgcn_update_dpp(0, __float_as_int(x), 0x111, 0xf, 0xf, true); x = fmaxf(x, __int_as_float(v)); // row_shr:1
    v = __builtin_amdgcn_update_dpp(0, __float_as_int(x), 0x112, 0xf, 0xf, true); x = fmaxf(x, __int_as_float(v)); // row_shr:2
    v = __builtin_amdgcn_update_dpp(0, __float_as_int(x), 0x114, 0xf, 0xf, true); x = fmaxf(x, __int_as_float(v)); // row_shr:4
    v = __builtin_amdgcn_update_dpp(0, __float_as_int(x), 0x118, 0xf, 0xf, true); x = fmaxf(x, __int_as_float(v)); // row_shr:8
    v = __builtin_amdgcn_update_dpp(0, __float_as_int(x), 0x142, 0xf, 0xf, true); x = fmaxf(x, __int_as_float(v)); // row_bcast:15
    v = __builtin_amdgcn_update_dpp(0, __float_as_int(x), 0x143, 0xf, 0xf, true); x = fmaxf(x, __int_as_float(v)); // row_bcast:31
    return x;
}

__device__ __forceinline__ float rdlane_f(float x, int l) {
    return __int_as_float(__builtin_amdgcn_readlane(__float_as_int(x), l));
}

// One block per batch, one wave per block. Speculative pipelined winner recurrence.
// Writes idx (as float), vals, one-hot w rows, soma (== vals).
__global__ __launch_bounds__(64) void k1_seq(const float* __restrict__ d2,
                                             float* __restrict__ out_idx,
                                             float* __restrict__ out_vals,
                                             float* __restrict__ out_w,
                                             float* __restrict__ out_soma) {
    const int b    = blockIdx.x;
    const int lane = threadIdx.x;
    const float* p = d2 + ((size_t)b << 18) + lane;      // b*L*K + lane
    float* pw      = out_w + ((size_t)b << 18) + lane;   // one-hot row base

    // 32-deep register prefetch ring
    float buf[32];
#pragma unroll
    for (int u = 0; u < 32; ++u) buf[u] = p[(size_t)u << 6];

    // t=0 setup: z0 = 0. With zd=za=0 and spec1==spec0, the generic resolution
    // below degenerates to a plain first-index argmax of spec0 for any s_w.
    float zd = 0.0f, za = 0.0f;
    float spec0 = __fadd_rn(buf[0], __fmul_rn(GAIN, 0.0f));  // == d2_0 bitwise
    float spec1 = spec0;
    float vM0 = rdlane_f(wave_max_to63(spec0), 63);
    int   s_w = 63;

    float idx_hold = 0.0f, val_hold = 0.0f;

    for (int g = 0; g < 128; ++g) {
        const int base32 = (g & 1) << 5;   // (t & 63) == base32 + u
#pragma unroll
        for (int u = 0; u < 32; ++u) {
            const int t = (g << 5) + u;

            // ---- resolve winner of step t (scalar path, ~30 cy) ----
            float sp1w = rdlane_f(spec1, s_w);           // true score of prev winner
            float vM   = fmaxf(vM0, sp1w);               // true max of step t
            unsigned long long b0 = __ballot(spec0 == vM);
            unsigned long long b1 = __ballot(spec1 == vM);
            unsigned long long wbit = 1ull << s_w;
            unsigned long long cand = (b0 & ~wbit) | (b1 & wbit);
            int w = (int)__ffsll((long long)cand) - 1;

            // ---- true z_t (uses OLD s_w) ----
            float z = (lane == s_w) ? za : zd;

            // ---- outputs for step t ----
            float d2v = buf[u];                          // d2_t (still live)
            float val = rdlane_f(d2v, w);
            float hard = (lane == w) ? 1.0f : 0.0f;
            pw[(size_t)t << 6] = hard;                   // coalesced one-hot row
            if (lane == base32 + u) { idx_hold = (float)w; val_hold = val; }

            // ---- prefetch d2_{t+32} into this slot ----
            int tn = t + 32; if (tn > L_DIM - 1) tn = L_DIM - 1;
            buf[u] = p[(size_t)tn << 6];

            // ---- speculative setup for step t+1 (vector path, overlaps resolution) ----
            zd = __fmul_rn(z, DECAY);                    // z_{t+1} if lane lost step t
            za = __fadd_rn(zd, 1.0f);                    // z_{t+1} if lane won step t
            float d2n = buf[(u + 1) & 31];               // d2_{t+1}
            spec0 = __fadd_rn(d2n, __fmul_rn(GAIN, zd));
            spec1 = __fadd_rn(d2n, __fmul_rn(GAIN, za));
            vM0 = rdlane_f(wave_max_to63(spec0), 63);

            s_w = w;

            // ---- coalesced idx/vals/soma store every 64 steps ----
            if (u == 31 && (g & 1)) {
                size_t o = ((size_t)b << 12) + ((size_t)(g >> 1) << 6) + lane;
                out_idx[o]  = idx_hold;
                out_vals[o] = val_hold;
                out_soma[o] = val_hold;   // soma == vals (w is one-hot, winner weight 1.0)
            }
        }
    }
}

extern "C" void kernel_launch(void* const* d_in, const int* in_sizes, int n_in,
                              void* d_out, int out_size, void* d_ws, size_t ws_size,
                              hipStream_t stream) {
    (void)in_sizes; (void)n_in; (void)out_size; (void)d_ws; (void)ws_size;

    const float* d2 = (const float*)d_in[0];
    float* out = (float*)d_out;

    const size_t BL = (size_t)B_DIM * L_DIM;          // 262144
    float* out_idx  = out;                            // [B, L]
    float* out_vals = out + BL;                       // [B, L]
    float* out_w    = out + 2 * BL;                   // [B, L, K]
    float* out_soma = out + 2 * BL + BL * K_DIM;      // [B, L]

    hipLaunchKernelGGL(k1_seq, dim3(B_DIM), dim3(64), 0, stream,
                       d2, out_idx, out_vals, out_w, out_soma);
}